// Round 7
// baseline (253.491 us; speedup 1.0000x reference)
//
#include <hip/hip_runtime.h>
#include <hip/hip_bf16.h>
#include <math.h>

#define D 64
#define K_CODES 8192
#define M_QUERIES 32768
#define SLICES 4
#define CODES_PER_SLICE (K_CODES / SLICES)  // 2048
#define CHUNK 64
#define NCHUNK (CODES_PER_SLICE / CHUNK)    // 32
#define QPB 128                              // queries per block = 4 waves * 32
#define TAU_V 4e-3f                          // gap threshold in v units (d2 gap = 2*v gap)

typedef __attribute__((ext_vector_type(8))) short bf16x8;
typedef __attribute__((ext_vector_type(4))) float f32x4;
typedef __attribute__((ext_vector_type(16))) float f32x16;

__device__ __forceinline__ unsigned short f2bf(float x) {
    __hip_bfloat16 h = __float2bfloat16(x);
    return *reinterpret_cast<unsigned short*>(&h);
}
__device__ __forceinline__ float bf2f(unsigned short s) {
    __hip_bfloat16 h;
    *reinterpret_cast<unsigned short*>(&h) = s;
    return __bfloat162float(h);
}

// ---- K0: split emb into bf16 hi/lo, he' = 0.5*||e||^2 + 128, zero counter ----
__global__ __launch_bounds__(256) void k0_split(const float* __restrict__ emb,
                                                unsigned short* __restrict__ e_hi,
                                                unsigned short* __restrict__ e_lo,
                                                float* __restrict__ halfee,
                                                int* __restrict__ ws_cnt) {
    const int wid = threadIdx.x >> 6, l = threadIdx.x & 63;
    const int c = blockIdx.x * 4 + wid;
    if (c == 0 && l == 0) *ws_cnt = 0;
    float e = emb[(size_t)c * D + l];
    unsigned short h = f2bf(e);
    float r = e - bf2f(h);
    e_hi[(size_t)c * D + l] = h;
    e_lo[(size_t)c * D + l] = f2bf(r);
    float s = e * e;
#pragma unroll
    for (int m = 1; m < 64; m <<= 1) s += __shfl_xor(s, m);
    if (l == 0) halfee[c] = 0.5f * s + 128.0f;
}

// ---- K1: 32x32x16 MFMA scoring v = he' - z.e (bf16 split), packed top-2 ----
// Register budget is the constraint (allocator targets 4 waves/SIMD = 128
// unified VGPRs when LDS allows 4 blocks/CU). 32x32 MFMA halves the
// query-fragment footprint: qh[4]+ql[4]=32 VGPR, acc 2x16=32, staging 20,
// peak ~115 < 128 -> no spill (vs 16x16 body's ~145 -> 46MB spill).
__global__ __launch_bounds__(256, 1) void k1_mfma(const float* __restrict__ z,
                                                  const unsigned short* __restrict__ e_hi,
                                                  const unsigned short* __restrict__ e_lo,
                                                  const float* __restrict__ halfee,
                                                  float4* __restrict__ ws_part) {
    __shared__ unsigned short ldshi[2][CHUNK * 64];
    __shared__ unsigned short ldslo[2][CHUNK * 64];
    __shared__ float ldshe[2][CHUNK];

    const int tid = threadIdx.x;
    const int wid = tid >> 6;
    const int l   = tid & 63;
    const int col = l & 31;      // query column within wave's 32
    const int hi  = l >> 5;      // k-subgroup / code-row offset selector
    const int slice = blockIdx.y;
    const int cslice0 = slice * CODES_PER_SLICE;

    // this wave's 32 queries -> negated bf16 hi/lo B-fragments (one query/lane-pair)
    const int qw0 = blockIdx.x * QPB + wid * 32;
    const int qrow = qw0 + col;
    bf16x8 qh[4], ql[4];
#pragma unroll
    for (int kk = 0; kk < 4; ++kk) {
        const float* src = z + (size_t)qrow * D + kk * 16 + hi * 8;
        float4 f0 = *(const float4*)(src);
        float4 f1 = *(const float4*)(src + 4);
        float f[8] = {f0.x, f0.y, f0.z, f0.w, f1.x, f1.y, f1.z, f1.w};
        bf16x8 h, lo;
#pragma unroll
        for (int j = 0; j < 8; ++j) {
            float x = -f[j];
            unsigned short hh = f2bf(x);
            float r = x - bf2f(hh);
            h[j]  = (short)hh;
            lo[j] = (short)f2bf(r);
        }
        qh[kk] = h;
        ql[kk] = lo;
    }

    float g1 = 1e30f, g2 = 1e30f;
    int   gi = 0x7fffffff;
    float4 rh[2], rl[2], rhe;

    const int rowbase = (l & 31) * 128;      // tile0 row byte base (tile1 = +4096)
    const int swrow   = l & 7;               // row bits used by the XOR swizzle

#define ISSUE_LOADS(c1)                                                          \
    {                                                                            \
        const char* bhi = (const char*)e_hi + (size_t)(cslice0 + (c1) * CHUNK) * 128; \
        const char* blo = (const char*)e_lo + (size_t)(cslice0 + (c1) * CHUNK) * 128; \
        _Pragma("unroll") for (int p = 0; p < 2; ++p) {                          \
            int idx = p * 256 + tid;                                             \
            rh[p] = *(const float4*)(bhi + idx * 16);                            \
            rl[p] = *(const float4*)(blo + idx * 16);                            \
        }                                                                        \
        if (tid < 16)                                                            \
            rhe = *(const float4*)((const char*)halfee +                         \
                                   (size_t)(cslice0 + (c1) * CHUNK) * 4 + tid * 16); \
    }

#define WRITE_LDS(buf)                                                           \
    {                                                                            \
        _Pragma("unroll") for (int p = 0; p < 2; ++p) {                          \
            int idx = p * 256 + tid;                                             \
            int r = idx >> 3, cc = idx & 7;                                      \
            int off = r * 128 + (cc ^ (r & 7)) * 16;                             \
            *(float4*)((char*)ldshi[buf] + off) = rh[p];                         \
            *(float4*)((char*)ldslo[buf] + off) = rl[p];                         \
        }                                                                        \
        if (tid < 16) *(float4*)((char*)ldshe[buf] + tid * 16) = rhe;            \
    }

#define COMPUTE(bufc, cbase)                                                     \
    {                                                                            \
        const char*  bh  = (const char*)ldshi[bufc];                             \
        const char*  bl  = (const char*)ldslo[bufc];                             \
        const float* bhe = ldshe[bufc];                                          \
        f32x16 acc0, acc1;                                                       \
        _Pragma("unroll") for (int g = 0; g < 4; ++g) {                          \
            f32x4 h0 = *(const f32x4*)(bhe + g * 8 + 4 * hi);                    \
            f32x4 h1 = *(const f32x4*)(bhe + 32 + g * 8 + 4 * hi);               \
            acc0[g * 4 + 0] = h0[0]; acc0[g * 4 + 1] = h0[1];                    \
            acc0[g * 4 + 2] = h0[2]; acc0[g * 4 + 3] = h0[3];                    \
            acc1[g * 4 + 0] = h1[0]; acc1[g * 4 + 1] = h1[1];                    \
            acc1[g * 4 + 2] = h1[2]; acc1[g * 4 + 3] = h1[3];                    \
        }                                                                        \
        _Pragma("unroll") for (int kk = 0; kk < 4; ++kk) {                       \
            int sw = ((kk * 2 + hi) ^ swrow) * 16;                               \
            int a0 = rowbase + sw;                                               \
            bf16x8 ah0 = *(const bf16x8*)(bh + a0);                              \
            bf16x8 ah1 = *(const bf16x8*)(bh + a0 + 4096);                       \
            bf16x8 al0 = *(const bf16x8*)(bl + a0);                              \
            bf16x8 al1 = *(const bf16x8*)(bl + a0 + 4096);                       \
            acc0 = __builtin_amdgcn_mfma_f32_32x32x16_bf16(ah0, qh[kk], acc0, 0, 0, 0); \
            acc1 = __builtin_amdgcn_mfma_f32_32x32x16_bf16(ah1, qh[kk], acc1, 0, 0, 0); \
            acc0 = __builtin_amdgcn_mfma_f32_32x32x16_bf16(ah0, ql[kk], acc0, 0, 0, 0); \
            acc1 = __builtin_amdgcn_mfma_f32_32x32x16_bf16(ah1, ql[kk], acc1, 0, 0, 0); \
            acc0 = __builtin_amdgcn_mfma_f32_32x32x16_bf16(al0, qh[kk], acc0, 0, 0, 0); \
            acc1 = __builtin_amdgcn_mfma_f32_32x32x16_bf16(al1, qh[kk], acc1, 0, 0, 0); \
        }                                                                        \
        float m1p = 1e30f, m2p = 1e30f;                                          \
        _Pragma("unroll") for (int r = 0; r < 16; ++r) {                         \
            float vp0 = __int_as_float((__float_as_int(acc0[r]) & 0xFFFFFFE0) | r); \
            m2p = __builtin_amdgcn_fmed3f(vp0, m1p, m2p);                        \
            m1p = fminf(m1p, vp0);                                               \
            float vp1 = __int_as_float((__float_as_int(acc1[r]) & 0xFFFFFFE0) | (16 + r)); \
            m2p = __builtin_amdgcn_fmed3f(vp1, m1p, m2p);                        \
            m1p = fminf(m1p, vp1);                                               \
        }                                                                        \
        int p1 = __float_as_int(m1p) & 31;                                       \
        int rr = p1 & 15;                                                        \
        int code = (cbase) + (p1 >> 4) * 32 + (rr & 3) + 8 * (rr >> 2) + 4 * hi; \
        bool lt = m1p < g1;                                                      \
        g2 = fminf(lt ? g1 : g2, lt ? m2p : m1p);                                \
        g1 = lt ? m1p : g1;                                                      \
        gi = lt ? code : gi;                                                     \
    }

    ISSUE_LOADS(0);
    WRITE_LDS(0);
    __syncthreads();
    for (int c = 0; c < NCHUNK; ++c) {
        const int cur = c & 1;
        if (c + 1 < NCHUNK) ISSUE_LOADS(c + 1);
        COMPUTE(cur, cslice0 + c * CHUNK);
        __syncthreads();
        if (c + 1 < NCHUNK) WRITE_LDS(cur ^ 1);
        __syncthreads();
    }

    // lanes l and l^32 share a query column, hold disjoint code rows
    {
        float o1 = __shfl_xor(g1, 32);
        float o2 = __shfl_xor(g2, 32);
        int   oi = __shfl_xor(gi, 32);
        bool  take = (o1 < g1) || (o1 == g1 && oi < gi);
        float n2   = take ? fminf(o2, g1) : fminf(g2, o1);
        g1 = take ? o1 : g1;
        gi = take ? oi : gi;
        g2 = n2;
        if (l < 32) {
            int q = qw0 + col;
            ws_part[(size_t)q * SLICES + slice] =
                make_float4(g1, g2, __int_as_float(gi), 0.f);
        }
    }
#undef ISSUE_LOADS
#undef WRITE_LDS
#undef COMPUTE
}

// ---- K1b: merge slices, flag near-ties ----
__global__ __launch_bounds__(256) void k1b_merge(const float4* __restrict__ ws_part,
                                                 int* __restrict__ ws_idx,
                                                 int* __restrict__ ws_cnt,
                                                 int* __restrict__ ws_list) {
    int q = blockIdx.x * blockDim.x + threadIdx.x;
    float m1 = 1e30f, m2 = 1e30f;
    int   i1 = 0x7fffffff;
#pragma unroll
    for (int s = 0; s < SLICES; ++s) {
        float4 p = ws_part[(size_t)q * SLICES + s];
        float v1 = p.x, v2 = p.y;
        int   vi = __float_as_int(p.z);
        if (v1 < m1 || (v1 == m1 && vi < i1)) { m2 = fminf(m1, v2); m1 = v1; i1 = vi; }
        else                                  { m2 = fminf(m2, v1); }
    }
    ws_idx[q] = i1;
    if (m2 - m1 < TAU_V) {
        int r = atomicAdd(ws_cnt, 1);
        ws_list[r] = q;
    }
}

// ---- K2: fp64 exact rescan for near-tie queries ----
__global__ __launch_bounds__(256) void k2_rescue(const float* __restrict__ z,
                                                 const float* __restrict__ emb,
                                                 const int* __restrict__ ws_cnt,
                                                 const int* __restrict__ ws_list,
                                                 int* __restrict__ ws_idx) {
    __shared__ float  zrow[D];
    __shared__ double rv[256];
    __shared__ int    ri[256];
    const int cnt = *ws_cnt;
    for (int r = blockIdx.x; r < cnt; r += gridDim.x) {
        const int q = ws_list[r];
        __syncthreads();
        if (threadIdx.x < D) zrow[threadIdx.x] = z[(size_t)q * D + threadIdx.x];
        __syncthreads();
        double best = 1e300;
        int    bi   = 0x7fffffff;
        for (int c = threadIdx.x; c < K_CODES; c += 256) {
            const float4* er = (const float4*)(emb + (size_t)c * D);
            double acc = 0.0;
#pragma unroll
            for (int k = 0; k < 16; ++k) {
                float4 e  = er[k];
                double d0 = (double)zrow[4 * k + 0] - (double)e.x;
                double d1 = (double)zrow[4 * k + 1] - (double)e.y;
                double d2 = (double)zrow[4 * k + 2] - (double)e.z;
                double d3 = (double)zrow[4 * k + 3] - (double)e.w;
                acc += d0 * d0 + d1 * d1 + d2 * d2 + d3 * d3;
            }
            if (acc < best) { best = acc; bi = c; }
        }
        rv[threadIdx.x] = best;
        ri[threadIdx.x] = bi;
        __syncthreads();
        for (int s = 128; s > 0; s >>= 1) {
            if (threadIdx.x < s) {
                double ov = rv[threadIdx.x + s];
                int    oi = ri[threadIdx.x + s];
                if (ov < rv[threadIdx.x] || (ov == rv[threadIdx.x] && oi < ri[threadIdx.x])) {
                    rv[threadIdx.x] = ov;
                    ri[threadIdx.x] = oi;
                }
            }
            __syncthreads();
        }
        if (threadIdx.x == 0) ws_idx[q] = ri[0];
        __syncthreads();
    }
}

// ---- K3: gather z_q, emit idx as float, per-block loss partials ----
__global__ __launch_bounds__(256) void k3_gather(const float* __restrict__ emb,
                                                 const float* __restrict__ z,
                                                 const int* __restrict__ ws_idx,
                                                 float* __restrict__ out,
                                                 float* __restrict__ partial) {
    __shared__ float sb[256];
    int g = blockIdx.x * 256 + threadIdx.x;
    int q = g >> 6, d = g & 63;
    int id = ws_idx[q];
    float e = emb[(size_t)id * D + d];
    out[g] = e;
    if (d == 0) out[(size_t)M_QUERIES * D + q] = (float)id;
    float df = e - z[g];
    sb[threadIdx.x] = df * df;
    __syncthreads();
    for (int s = 128; s > 0; s >>= 1) {
        if (threadIdx.x < s) sb[threadIdx.x] += sb[threadIdx.x + s];
        __syncthreads();
    }
    if (threadIdx.x == 0) partial[blockIdx.x] = sb[0];
}

// ---- K4: final loss reduce ----
__global__ __launch_bounds__(256) void k4_loss(const float* __restrict__ partial,
                                               float* __restrict__ out) {
    __shared__ double sb[256];
    double s = 0.0;
    for (int i = threadIdx.x; i < (M_QUERIES * D) / 256; i += 256) s += (double)partial[i];
    sb[threadIdx.x] = s;
    __syncthreads();
    for (int st = 128; st > 0; st >>= 1) {
        if (threadIdx.x < st) sb[threadIdx.x] += sb[threadIdx.x + st];
        __syncthreads();
    }
    if (threadIdx.x == 0)
        out[(size_t)M_QUERIES * D + M_QUERIES] =
            (float)(1.25 * sb[0] / (double)((size_t)M_QUERIES * D));
}

extern "C" void kernel_launch(void* const* d_in, const int* in_sizes, int n_in,
                              void* d_out, int out_size, void* d_ws, size_t ws_size,
                              hipStream_t stream) {
    const float* z   = (const float*)d_in[0];
    const float* emb = (const float*)d_in[1];
    float* out = (float*)d_out;
    char*  ws  = (char*)d_ws;

    unsigned short* e_hi    = (unsigned short*)(ws);                    // 1 MB
    unsigned short* e_lo    = (unsigned short*)(ws + 1048576);          // 1 MB
    float*          halfee  = (float*)(ws + 2097152);                   // 32 KB
    float4*         ws_part = (float4*)(ws + 2129920);                  // 2 MB
    int*            ws_idx  = (int*)(ws + 2129920 + 2097152);           // 128 KB
    int*            ws_cnt  = (int*)(ws + 2129920 + 2097152 + 131072);  // 64 B
    int*            ws_list = (int*)(ws + 2129920 + 2097152 + 131136);  // 128 KB
    float*          partial = (float*)(ws + 2129920 + 2097152 + 262208);// 32 KB

    k0_split<<<K_CODES / 4, 256, 0, stream>>>(emb, e_hi, e_lo, halfee, ws_cnt);

    dim3 g1(M_QUERIES / QPB, SLICES);
    k1_mfma<<<g1, 256, 0, stream>>>(z, e_hi, e_lo, halfee, ws_part);

    k1b_merge<<<M_QUERIES / 256, 256, 0, stream>>>(ws_part, ws_idx, ws_cnt, ws_list);

    k2_rescue<<<256, 256, 0, stream>>>(z, emb, ws_cnt, ws_list, ws_idx);

    k3_gather<<<(M_QUERIES * D) / 256, 256, 0, stream>>>(emb, z, ws_idx, out, partial);

    k4_loss<<<1, 256, 0, stream>>>(partial, out);
}

// Round 8
// 193.865 us; speedup vs baseline: 1.3076x; 1.3076x over previous
//
#include <hip/hip_runtime.h>
#include <hip/hip_bf16.h>
#include <math.h>

#define D 64
#define K_CODES 8192
#define M_QUERIES 32768
#define SLICES 4
#define CODES_PER_SLICE (K_CODES / SLICES)  // 2048
#define CHUNK 64
#define NCHUNK (CODES_PER_SLICE / CHUNK)    // 32 chunks per slice
#define QPB 128                              // queries per block = 4 waves * 32
#define TAU_V 4e-3f                          // gap threshold in v units

typedef __attribute__((ext_vector_type(8))) short bf16x8;
typedef __attribute__((ext_vector_type(4))) float f32x4;
typedef __attribute__((ext_vector_type(16))) float f32x16;

__device__ __forceinline__ unsigned short f2bf(float x) {
    __hip_bfloat16 h = __float2bfloat16(x);
    return *reinterpret_cast<unsigned short*>(&h);
}
__device__ __forceinline__ float bf2f(unsigned short s) {
    __hip_bfloat16 h;
    *reinterpret_cast<unsigned short*>(&h) = s;
    return __bfloat162float(h);
}
__device__ __forceinline__ void gld_lds16(const void* g, void* l) {
    __builtin_amdgcn_global_load_lds(
        (const __attribute__((address_space(1))) void*)g,
        (__attribute__((address_space(3))) void*)l, 16, 0, 0);
}
__device__ __forceinline__ void gld_lds4(const void* g, void* l) {
    __builtin_amdgcn_global_load_lds(
        (const __attribute__((address_space(1))) void*)g,
        (__attribute__((address_space(3))) void*)l, 4, 0, 0);
}

// ---- K0: split emb into bf16 hi/lo in MFMA-FRAGMENT order ----
// Per 64-code chunk: layout [u=k-unit 0..7][code-in-chunk 0..63][16B],
// i.e. byte offset chunk*8192 + (u*64 + r)*16 holds codes' elems u*8..u*8+7.
// Makes k1's ds_read_b128 lane-contiguous (conflict-free) and the staging a
// linear copy eligible for global_load_lds.
__global__ __launch_bounds__(256) void k0_split(const float* __restrict__ emb,
                                                unsigned short* __restrict__ e_hi,
                                                unsigned short* __restrict__ e_lo,
                                                float* __restrict__ halfee,
                                                int* __restrict__ ws_cnt) {
    const int t = threadIdx.x;
    const int chunk = blockIdx.x;
    if (chunk == 0 && t == 0) *ws_cnt = 0;
    const int u = t & 7;
#pragma unroll
    for (int it = 0; it < 2; ++it) {
        const int r = (t >> 3) + it * 32;           // code within chunk
        const float* src = emb + ((size_t)(chunk * 64 + r) * 64 + u * 8);
        float4 f0 = *(const float4*)(src);
        float4 f1 = *(const float4*)(src + 4);
        float f[8] = {f0.x, f0.y, f0.z, f0.w, f1.x, f1.y, f1.z, f1.w};
        bf16x8 h, lo;
        float s = 0.f;
#pragma unroll
        for (int j = 0; j < 8; ++j) {
            float e = f[j];
            s += e * e;
            unsigned short hh = f2bf(e);
            h[j]  = (short)hh;
            lo[j] = (short)f2bf(e - bf2f(hh));
        }
        size_t off = (size_t)chunk * 8192 + (size_t)(u * 64 + r) * 16;
        *(bf16x8*)((char*)e_hi + off) = h;
        *(bf16x8*)((char*)e_lo + off) = lo;
        s += __shfl_xor(s, 1);
        s += __shfl_xor(s, 2);
        s += __shfl_xor(s, 4);
        if (u == 0) halfee[chunk * 64 + r] = 0.5f * s + 128.0f;
    }
}

// ---- K1: 32x32x16 MFMA scoring v = he' - z.e (bf16 split), packed top-2 ----
// Staging via global_load_lds (linear dest, no staging VGPRs, no staging VALU).
// Register budget: qh/ql 32 + acc 32 + ~20 misc ~= 90 < 128 -> no spill at
// 4 blocks/CU (33KB LDS) = 16 waves/CU.
__global__ __launch_bounds__(256, 1) void k1_mfma(const float* __restrict__ z,
                                                  const unsigned short* __restrict__ e_hi,
                                                  const unsigned short* __restrict__ e_lo,
                                                  const float* __restrict__ halfee,
                                                  float4* __restrict__ ws_part) {
    __shared__ __align__(16) unsigned short ldshi[2][CHUNK * 64];  // 8KB each buf
    __shared__ __align__(16) unsigned short ldslo[2][CHUNK * 64];
    __shared__ __align__(16) float ldshe[2][CHUNK];

    const int tid = threadIdx.x;
    const int wid = tid >> 6;
    const int l   = tid & 63;
    const int col = l & 31;      // query column within wave's 32
    const int hi  = l >> 5;      // k-subgroup selector
    const int slice = blockIdx.y;
    const int chunk0 = slice * NCHUNK;   // global chunk index base

    // this wave's 32 queries -> negated bf16 hi/lo B-fragments
    const int qw0 = blockIdx.x * QPB + wid * 32;
    const int qrow = qw0 + col;
    bf16x8 qh[4], ql[4];
#pragma unroll
    for (int kk = 0; kk < 4; ++kk) {
        const float* src = z + (size_t)qrow * D + kk * 16 + hi * 8;
        float4 f0 = *(const float4*)(src);
        float4 f1 = *(const float4*)(src + 4);
        float f[8] = {f0.x, f0.y, f0.z, f0.w, f1.x, f1.y, f1.z, f1.w};
        bf16x8 h, lo;
#pragma unroll
        for (int j = 0; j < 8; ++j) {
            float x = -f[j];
            unsigned short hh = f2bf(x);
            float r = x - bf2f(hh);
            h[j]  = (short)hh;
            lo[j] = (short)f2bf(r);
        }
        qh[kk] = h;
        ql[kk] = lo;
    }

    float g1 = 1e30f, g2 = 1e30f;
    int   gi = 0x7fffffff;

// async global->LDS staging: per wave 2x1KB for hi, 2x1KB for lo (8KB each
// buffer total across 4 waves); he 256B by wave 0. Dest is wave-uniform base,
// HW adds lane*size; source includes l*16 so src/dst orders match.
#define STAGE(buf, c1)                                                           \
    {                                                                            \
        size_t cb = (size_t)(chunk0 + (c1)) * 8192 + wid * 2048 + l * 16;        \
        const char* ghi = (const char*)e_hi + cb;                                \
        const char* glo = (const char*)e_lo + cb;                                \
        char* dhi = (char*)&ldshi[buf][0] + wid * 2048;                          \
        char* dlo = (char*)&ldslo[buf][0] + wid * 2048;                          \
        gld_lds16(ghi, dhi);                                                     \
        gld_lds16(ghi + 1024, dhi + 1024);                                       \
        gld_lds16(glo, dlo);                                                     \
        gld_lds16(glo + 1024, dlo + 1024);                                       \
        if (wid == 0)                                                            \
            gld_lds4((const char*)halfee + (size_t)(chunk0 + (c1)) * 256 + l * 4,\
                     (char*)&ldshe[buf][0]);                                     \
    }

#define COMPUTE(bufc, cbase)                                                     \
    {                                                                            \
        const char*  bh  = (const char*)ldshi[bufc];                             \
        const char*  bl  = (const char*)ldslo[bufc];                             \
        const float* bhe = ldshe[bufc];                                          \
        f32x16 acc0, acc1;                                                       \
        _Pragma("unroll") for (int g = 0; g < 4; ++g) {                          \
            f32x4 h0 = *(const f32x4*)(bhe + g * 8 + 4 * hi);                    \
            f32x4 h1 = *(const f32x4*)(bhe + 32 + g * 8 + 4 * hi);               \
            acc0[g * 4 + 0] = h0[0]; acc0[g * 4 + 1] = h0[1];                    \
            acc0[g * 4 + 2] = h0[2]; acc0[g * 4 + 3] = h0[3];                    \
            acc1[g * 4 + 0] = h1[0]; acc1[g * 4 + 1] = h1[1];                    \
            acc1[g * 4 + 2] = h1[2]; acc1[g * 4 + 3] = h1[3];                    \
        }                                                                        \
        _Pragma("unroll") for (int kk = 0; kk < 4; ++kk) {                       \
            int a0 = ((kk * 2 + hi) * 64 + col) * 16;   /* lane-contiguous */    \
            bf16x8 ah0 = *(const bf16x8*)(bh + a0);                              \
            bf16x8 ah1 = *(const bf16x8*)(bh + a0 + 512);                        \
            bf16x8 al0 = *(const bf16x8*)(bl + a0);                              \
            bf16x8 al1 = *(const bf16x8*)(bl + a0 + 512);                        \
            acc0 = __builtin_amdgcn_mfma_f32_32x32x16_bf16(ah0, qh[kk], acc0, 0, 0, 0); \
            acc1 = __builtin_amdgcn_mfma_f32_32x32x16_bf16(ah1, qh[kk], acc1, 0, 0, 0); \
            acc0 = __builtin_amdgcn_mfma_f32_32x32x16_bf16(ah0, ql[kk], acc0, 0, 0, 0); \
            acc1 = __builtin_amdgcn_mfma_f32_32x32x16_bf16(ah1, ql[kk], acc1, 0, 0, 0); \
            acc0 = __builtin_amdgcn_mfma_f32_32x32x16_bf16(al0, qh[kk], acc0, 0, 0, 0); \
            acc1 = __builtin_amdgcn_mfma_f32_32x32x16_bf16(al1, qh[kk], acc1, 0, 0, 0); \
        }                                                                        \
        float m1p = 1e30f, m2p = 1e30f;                                          \
        _Pragma("unroll") for (int r = 0; r < 16; ++r) {                         \
            float vp0 = __int_as_float((__float_as_int(acc0[r]) & 0xFFFFFFE0) | r); \
            m2p = __builtin_amdgcn_fmed3f(vp0, m1p, m2p);                        \
            m1p = fminf(m1p, vp0);                                               \
            float vp1 = __int_as_float((__float_as_int(acc1[r]) & 0xFFFFFFE0) | (16 + r)); \
            m2p = __builtin_amdgcn_fmed3f(vp1, m1p, m2p);                        \
            m1p = fminf(m1p, vp1);                                               \
        }                                                                        \
        int p1 = __float_as_int(m1p) & 31;                                       \
        int rr = p1 & 15;                                                        \
        int code = (cbase) + (p1 >> 4) * 32 + (rr & 3) + 8 * (rr >> 2) + 4 * hi; \
        bool lt = m1p < g1;                                                      \
        g2 = fminf(lt ? g1 : g2, lt ? m2p : m1p);                                \
        g1 = lt ? m1p : g1;                                                      \
        gi = lt ? code : gi;                                                     \
    }

    STAGE(0, 0);
    __syncthreads();   // compiler emits vmcnt(0) drain before barrier
    for (int c = 0; c < NCHUNK; ++c) {
        const int cur = c & 1;
        if (c + 1 < NCHUNK) STAGE(cur ^ 1, c + 1);
        COMPUTE(cur, slice * CODES_PER_SLICE + c * CHUNK);
        __syncthreads();
    }

    // lanes l and l^32 share a query column, hold disjoint code rows
    {
        float o1 = __shfl_xor(g1, 32);
        float o2 = __shfl_xor(g2, 32);
        int   oi = __shfl_xor(gi, 32);
        bool  take = (o1 < g1) || (o1 == g1 && oi < gi);
        float n2   = take ? fminf(o2, g1) : fminf(g2, o1);
        g1 = take ? o1 : g1;
        gi = take ? oi : gi;
        g2 = n2;
        if (l < 32) {
            int q = qw0 + col;
            ws_part[(size_t)q * SLICES + slice] =
                make_float4(g1, g2, __int_as_float(gi), 0.f);
        }
    }
#undef STAGE
#undef COMPUTE
}

// ---- K1b: merge slices, flag near-ties ----
__global__ __launch_bounds__(256) void k1b_merge(const float4* __restrict__ ws_part,
                                                 int* __restrict__ ws_idx,
                                                 int* __restrict__ ws_cnt,
                                                 int* __restrict__ ws_list) {
    int q = blockIdx.x * blockDim.x + threadIdx.x;
    float m1 = 1e30f, m2 = 1e30f;
    int   i1 = 0x7fffffff;
#pragma unroll
    for (int s = 0; s < SLICES; ++s) {
        float4 p = ws_part[(size_t)q * SLICES + s];
        float v1 = p.x, v2 = p.y;
        int   vi = __float_as_int(p.z);
        if (v1 < m1 || (v1 == m1 && vi < i1)) { m2 = fminf(m1, v2); m1 = v1; i1 = vi; }
        else                                  { m2 = fminf(m2, v1); }
    }
    ws_idx[q] = i1;
    if (m2 - m1 < TAU_V) {
        int r = atomicAdd(ws_cnt, 1);
        ws_list[r] = q;
    }
}

// ---- K2: fp64 exact rescan for near-tie queries ----
__global__ __launch_bounds__(256) void k2_rescue(const float* __restrict__ z,
                                                 const float* __restrict__ emb,
                                                 const int* __restrict__ ws_cnt,
                                                 const int* __restrict__ ws_list,
                                                 int* __restrict__ ws_idx) {
    __shared__ float  zrow[D];
    __shared__ double rv[256];
    __shared__ int    ri[256];
    const int cnt = *ws_cnt;
    for (int r = blockIdx.x; r < cnt; r += gridDim.x) {
        const int q = ws_list[r];
        __syncthreads();
        if (threadIdx.x < D) zrow[threadIdx.x] = z[(size_t)q * D + threadIdx.x];
        __syncthreads();
        double best = 1e300;
        int    bi   = 0x7fffffff;
        for (int c = threadIdx.x; c < K_CODES; c += 256) {
            const float4* er = (const float4*)(emb + (size_t)c * D);
            double acc = 0.0;
#pragma unroll
            for (int k = 0; k < 16; ++k) {
                float4 e  = er[k];
                double d0 = (double)zrow[4 * k + 0] - (double)e.x;
                double d1 = (double)zrow[4 * k + 1] - (double)e.y;
                double d2 = (double)zrow[4 * k + 2] - (double)e.z;
                double d3 = (double)zrow[4 * k + 3] - (double)e.w;
                acc += d0 * d0 + d1 * d1 + d2 * d2 + d3 * d3;
            }
            if (acc < best) { best = acc; bi = c; }
        }
        rv[threadIdx.x] = best;
        ri[threadIdx.x] = bi;
        __syncthreads();
        for (int s = 128; s > 0; s >>= 1) {
            if (threadIdx.x < s) {
                double ov = rv[threadIdx.x + s];
                int    oi = ri[threadIdx.x + s];
                if (ov < rv[threadIdx.x] || (ov == rv[threadIdx.x] && oi < ri[threadIdx.x])) {
                    rv[threadIdx.x] = ov;
                    ri[threadIdx.x] = oi;
                }
            }
            __syncthreads();
        }
        if (threadIdx.x == 0) ws_idx[q] = ri[0];
        __syncthreads();
    }
}

// ---- K3: gather z_q, emit idx as float, per-block loss partials ----
__global__ __launch_bounds__(256) void k3_gather(const float* __restrict__ emb,
                                                 const float* __restrict__ z,
                                                 const int* __restrict__ ws_idx,
                                                 float* __restrict__ out,
                                                 float* __restrict__ partial) {
    __shared__ float sb[256];
    int g = blockIdx.x * 256 + threadIdx.x;
    int q = g >> 6, d = g & 63;
    int id = ws_idx[q];
    float e = emb[(size_t)id * D + d];
    out[g] = e;
    if (d == 0) out[(size_t)M_QUERIES * D + q] = (float)id;
    float df = e - z[g];
    sb[threadIdx.x] = df * df;
    __syncthreads();
    for (int s = 128; s > 0; s >>= 1) {
        if (threadIdx.x < s) sb[threadIdx.x] += sb[threadIdx.x + s];
        __syncthreads();
    }
    if (threadIdx.x == 0) partial[blockIdx.x] = sb[0];
}

// ---- K4: final loss reduce ----
__global__ __launch_bounds__(256) void k4_loss(const float* __restrict__ partial,
                                               float* __restrict__ out) {
    __shared__ double sb[256];
    double s = 0.0;
    for (int i = threadIdx.x; i < (M_QUERIES * D) / 256; i += 256) s += (double)partial[i];
    sb[threadIdx.x] = s;
    __syncthreads();
    for (int st = 128; st > 0; st >>= 1) {
        if (threadIdx.x < st) sb[threadIdx.x] += sb[threadIdx.x + st];
        __syncthreads();
    }
    if (threadIdx.x == 0)
        out[(size_t)M_QUERIES * D + M_QUERIES] =
            (float)(1.25 * sb[0] / (double)((size_t)M_QUERIES * D));
}

extern "C" void kernel_launch(void* const* d_in, const int* in_sizes, int n_in,
                              void* d_out, int out_size, void* d_ws, size_t ws_size,
                              hipStream_t stream) {
    const float* z   = (const float*)d_in[0];
    const float* emb = (const float*)d_in[1];
    float* out = (float*)d_out;
    char*  ws  = (char*)d_ws;

    unsigned short* e_hi    = (unsigned short*)(ws);                    // 1 MB
    unsigned short* e_lo    = (unsigned short*)(ws + 1048576);          // 1 MB
    float*          halfee  = (float*)(ws + 2097152);                   // 32 KB
    float4*         ws_part = (float4*)(ws + 2129920);                  // 2 MB
    int*            ws_idx  = (int*)(ws + 2129920 + 2097152);           // 128 KB
    int*            ws_cnt  = (int*)(ws + 2129920 + 2097152 + 131072);  // 64 B
    int*            ws_list = (int*)(ws + 2129920 + 2097152 + 131136);  // 128 KB
    float*          partial = (float*)(ws + 2129920 + 2097152 + 262208);// 32 KB

    k0_split<<<K_CODES / 64, 256, 0, stream>>>(emb, e_hi, e_lo, halfee, ws_cnt);

    dim3 g1(M_QUERIES / QPB, SLICES);
    k1_mfma<<<g1, 256, 0, stream>>>(z, e_hi, e_lo, halfee, ws_part);

    k1b_merge<<<M_QUERIES / 256, 256, 0, stream>>>(ws_part, ws_idx, ws_cnt, ws_list);

    k2_rescue<<<256, 256, 0, stream>>>(z, emb, ws_cnt, ws_list, ws_idx);

    k3_gather<<<(M_QUERIES * D) / 256, 256, 0, stream>>>(emb, z, ws_idx, out, partial);

    k4_loss<<<1, 256, 0, stream>>>(partial, out);
}